// Round 6
// baseline (203.416 us; speedup 1.0000x reference)
//
#include <hip/hip_runtime.h>

// Volume rendering (NeRF-style fancy_integration), f32 in/out.
// B=4, R=32768, S=64 -> 131072 rays, 64 samples.
//
// Mapping (R4): wave = 4 rays per chunk; each 16-lane DPP row owns one ray;
// each lane owns 4 consecutive samples -> all global traffic is float4,
// fully lane-linear. Cross-lane = 4-step DPP row scans.
//
// R6: (1) nt on STORES only (outputs never re-read; don't evict the
// L3-resident inputs the harness restore just wrote) — R5 wrongly put nt
// on loads too, risking bypass of those hits (FETCH=82MB<168MB proved
// residency). (2) Each wave handles 2 chunks (8 rays) with all 10 loads
// issued before any compute: 10KB in flight per wave, half the turnover.
// Context: harness poison fill (402MB @6.7TB/s) drains concurrently with
// our kernel; we are sharing HBM with it, so maximize our MLP.

#define EPS_W 1e-10f
#define DELTA_INF_V 1e10f

#define DPP_ROW_SHL(n) (0x100 | (n))
#define DPP_ROW_SHR(n) (0x110 | (n))

using f4 = __attribute__((ext_vector_type(4))) float;

template <int CTRL>
__device__ __forceinline__ float dpp_mov(float x, float old) {
    return __builtin_bit_cast(float,
        __builtin_amdgcn_update_dpp(
            __builtin_bit_cast(int, old), __builtin_bit_cast(int, x),
            CTRL, 0xf, 0xf, false));
}

// Inclusive multiply-scan within each 16-lane row (identity 1.0).
__device__ __forceinline__ float row_scan_mul(float p) {
    p *= dpp_mov<DPP_ROW_SHR(1)>(p, 1.0f);
    p *= dpp_mov<DPP_ROW_SHR(2)>(p, 1.0f);
    p *= dpp_mov<DPP_ROW_SHR(4)>(p, 1.0f);
    p *= dpp_mov<DPP_ROW_SHR(8)>(p, 1.0f);
    return p;
}

// Row sum; lane 15 of each row ends with the full row total.
__device__ __forceinline__ float row_sum(float x) {
    x += dpp_mov<DPP_ROW_SHR(1)>(x, 0.0f);
    x += dpp_mov<DPP_ROW_SHR(2)>(x, 0.0f);
    x += dpp_mov<DPP_ROW_SHR(4)>(x, 0.0f);
    x += dpp_mov<DPP_ROW_SHR(8)>(x, 0.0f);
    return x;
}

#define CPW 2   // chunks (of 4 rays / 256 samples) per wave

__global__ __launch_bounds__(256) void volrend_kernel(
    const float* __restrict__ rgb,      // [n_rays, 64, 3]
    const float* __restrict__ sigma,    // [n_rays, 64]
    const float* __restrict__ z_vals,   // [n_rays, 64]
    float* __restrict__ rgb_out,        // [n_rays, 3]
    float* __restrict__ depth_out,      // [n_rays]
    float* __restrict__ weights_out,    // [n_rays, 64]
    int n_rays)
{
    const int lane = threadIdx.x & 63;
    const int wave = threadIdx.x >> 6;
    const long long wave_g = (long long)blockIdx.x * (blockDim.x >> 6) + wave;

    const int j   = lane & 15;   // lane within row: samples 4j..4j+3
    const int row = lane >> 4;   // ray within chunk

    const long long chunk0 = wave_g * CPW;
    const int n_chunks = n_rays >> 2;

    // ---- issue ALL loads up front (10 x dwordx4 per lane in flight) ----
    f4 sg[CPW], zz[CPW], c0[CPW], c1[CPW], c2[CPW];
    bool live[CPW];
    #pragma unroll
    for (int k = 0; k < CPW; ++k) {
        const long long ch = chunk0 + k;
        live[k] = (ch < n_chunks);
        const long long chs = live[k] ? ch : (n_chunks - 1);  // safe addr
        sg[k] = *(reinterpret_cast<const f4*>(sigma  + chs * 256) + lane);
        zz[k] = *(reinterpret_cast<const f4*>(z_vals + chs * 256) + lane);
        const f4* rgb4 = reinterpret_cast<const f4*>(rgb + chs * 768 + (long long)lane * 12);
        c0[k] = rgb4[0];   // r0 g0 b0 r1
        c1[k] = rgb4[1];   // g1 b1 r2 g2
        c2[k] = rgb4[2];   // b2 r3 g3 b3
    }

    #pragma unroll
    for (int k = 0; k < CPW; ++k) {
        if (!live[k]) break;
        const long long ch  = chunk0 + k;
        const long long ray = ch * 4 + row;

        // ---- deltas ----
        const float zn = dpp_mov<DPP_ROW_SHL(1)>(zz[k].x, 0.0f); // next lane z0
        const float d0 = zz[k].y - zz[k].x;
        const float d1 = zz[k].z - zz[k].y;
        const float d2 = zz[k].w - zz[k].z;
        const float d3 = (j == 15) ? DELTA_INF_V : (zn - zz[k].w);

        // ---- alpha = 1 - exp(-delta * relu(sigma)) ----
        const float a0 = 1.0f - __expf(-d0 * fmaxf(sg[k].x, 0.0f));
        const float a1 = 1.0f - __expf(-d1 * fmaxf(sg[k].y, 0.0f));
        const float a2 = 1.0f - __expf(-d2 * fmaxf(sg[k].z, 0.0f));
        const float a3 = 1.0f - __expf(-d3 * fmaxf(sg[k].w, 0.0f));

        // ---- exclusive cumprod of (1 - a + eps) ----
        const float q0 = 1.0f - a0 + EPS_W;
        const float q1 = 1.0f - a1 + EPS_W;
        const float q2 = 1.0f - a2 + EPS_W;
        const float q3 = 1.0f - a3 + EPS_W;
        const float P0 = q0;
        const float P1 = P0 * q1;
        const float P2 = P1 * q2;
        const float P3 = P2 * q3;

        const float R = row_scan_mul(P3);
        const float E = dpp_mov<DPP_ROW_SHR(1)>(R, 1.0f);  // lane0 = 1

        const float w0 = a0 * E;
        const float w1 = a1 * (E * P0);
        const float w2 = a2 * (E * P1);
        const float w3 = a3 * (E * P2);

        // ---- weights: one contiguous nt float4 store per lane ----
        f4 wv; wv.x = w0; wv.y = w1; wv.z = w2; wv.w = w3;
        __builtin_nontemporal_store(
            wv, reinterpret_cast<f4*>(weights_out + ch * 256) + lane);

        // ---- weighted sums (rgb + depth) ----
        float pr = w0 * c0[k].x + w1 * c0[k].w + w2 * c1[k].z + w3 * c2[k].y;
        float pg = w0 * c0[k].y + w1 * c1[k].x + w2 * c1[k].w + w3 * c2[k].z;
        float pb = w0 * c0[k].z + w1 * c1[k].y + w2 * c2[k].x + w3 * c2[k].w;
        float pd = w0 * zz[k].x + w1 * zz[k].y + w2 * zz[k].z + w3 * zz[k].w;

        pr = row_sum(pr);
        pg = row_sum(pg);
        pb = row_sum(pb);
        pd = row_sum(pd);

        if (j == 15) {
            __builtin_nontemporal_store(pr, rgb_out + ray * 3 + 0);
            __builtin_nontemporal_store(pg, rgb_out + ray * 3 + 1);
            __builtin_nontemporal_store(pb, rgb_out + ray * 3 + 2);
            __builtin_nontemporal_store(pd, depth_out + ray);
        }
    }
}

extern "C" void kernel_launch(void* const* d_in, const int* in_sizes, int n_in,
                              void* d_out, int out_size, void* d_ws, size_t ws_size,
                              hipStream_t stream) {
    const float* rgb    = (const float*)d_in[0];   // [B,R,S,3]
    const float* sigma  = (const float*)d_in[1];   // [B,R,S,1]
    const float* z_vals = (const float*)d_in[2];   // [B,R,S,1]

    const int n_rays = in_sizes[1] / 64;           // B*R = 131072

    float* out         = (float*)d_out;
    float* rgb_out     = out;                              // n_rays*3
    float* depth_out   = out + (long long)n_rays * 3;      // n_rays
    float* weights_out = out + (long long)n_rays * 4;      // n_rays*64

    const int block = 256;                         // 4 waves/block
    const int rays_per_block = (block / 64) * 4 * CPW;   // 32
    const int grid = (n_rays + rays_per_block - 1) / rays_per_block;  // 4096

    volrend_kernel<<<grid, block, 0, stream>>>(
        rgb, sigma, z_vals, rgb_out, depth_out, weights_out, n_rays);
}

// Round 7
// 196.327 us; speedup vs baseline: 1.0361x; 1.0361x over previous
//
#include <hip/hip_runtime.h>

// Volume rendering (NeRF-style fancy_integration), f32 in/out.
// B=4, R=32768, S=64 -> 131072 rays, 64 samples.
//
// Mapping: wave = 4 rays per chunk; each 16-lane DPP row owns one ray;
// each lane owns 4 consecutive samples -> all global traffic is float4,
// fully lane-linear. Cross-lane = 4-step DPP row scans.
//
// R7: R6 structure (CPW=2, all 10 loads issued up front) + NON-TEMPORAL
// LOADS restored. Cross-round evidence: R4 (no nt)=70us, R5 (nt both)~61us,
// R6 (nt stores only)=71us -> nt loads are worth 10-15% here. R5's FETCH
// stayed 82MB, so nt loads still hit L3 but skip allocation/eviction work
// in caches freshly dirtied by the harness's 570MB restore+poison traffic.

#define EPS_W 1e-10f
#define DELTA_INF_V 1e10f

#define DPP_ROW_SHL(n) (0x100 | (n))
#define DPP_ROW_SHR(n) (0x110 | (n))

using f4 = __attribute__((ext_vector_type(4))) float;

template <int CTRL>
__device__ __forceinline__ float dpp_mov(float x, float old) {
    return __builtin_bit_cast(float,
        __builtin_amdgcn_update_dpp(
            __builtin_bit_cast(int, old), __builtin_bit_cast(int, x),
            CTRL, 0xf, 0xf, false));
}

// Inclusive multiply-scan within each 16-lane row (identity 1.0).
__device__ __forceinline__ float row_scan_mul(float p) {
    p *= dpp_mov<DPP_ROW_SHR(1)>(p, 1.0f);
    p *= dpp_mov<DPP_ROW_SHR(2)>(p, 1.0f);
    p *= dpp_mov<DPP_ROW_SHR(4)>(p, 1.0f);
    p *= dpp_mov<DPP_ROW_SHR(8)>(p, 1.0f);
    return p;
}

// Row sum; lane 15 of each row ends with the full row total.
__device__ __forceinline__ float row_sum(float x) {
    x += dpp_mov<DPP_ROW_SHR(1)>(x, 0.0f);
    x += dpp_mov<DPP_ROW_SHR(2)>(x, 0.0f);
    x += dpp_mov<DPP_ROW_SHR(4)>(x, 0.0f);
    x += dpp_mov<DPP_ROW_SHR(8)>(x, 0.0f);
    return x;
}

#define CPW 2   // chunks (of 4 rays / 256 samples) per wave

__global__ __launch_bounds__(256) void volrend_kernel(
    const float* __restrict__ rgb,      // [n_rays, 64, 3]
    const float* __restrict__ sigma,    // [n_rays, 64]
    const float* __restrict__ z_vals,   // [n_rays, 64]
    float* __restrict__ rgb_out,        // [n_rays, 3]
    float* __restrict__ depth_out,      // [n_rays]
    float* __restrict__ weights_out,    // [n_rays, 64]
    int n_rays)
{
    const int lane = threadIdx.x & 63;
    const int wave = threadIdx.x >> 6;
    const long long wave_g = (long long)blockIdx.x * (blockDim.x >> 6) + wave;

    const int j   = lane & 15;   // lane within row: samples 4j..4j+3
    const int row = lane >> 4;   // ray within chunk

    const long long chunk0 = wave_g * CPW;
    const int n_chunks = n_rays >> 2;

    // ---- issue ALL loads up front (10 x nt dwordx4 per lane in flight) ----
    f4 sg[CPW], zz[CPW], c0[CPW], c1[CPW], c2[CPW];
    bool live[CPW];
    #pragma unroll
    for (int k = 0; k < CPW; ++k) {
        const long long ch = chunk0 + k;
        live[k] = (ch < n_chunks);
        const long long chs = live[k] ? ch : (n_chunks - 1);  // safe addr
        sg[k] = __builtin_nontemporal_load(
            reinterpret_cast<const f4*>(sigma + chs * 256) + lane);
        zz[k] = __builtin_nontemporal_load(
            reinterpret_cast<const f4*>(z_vals + chs * 256) + lane);
        const f4* rgb4 = reinterpret_cast<const f4*>(rgb + chs * 768 + (long long)lane * 12);
        c0[k] = __builtin_nontemporal_load(rgb4 + 0);   // r0 g0 b0 r1
        c1[k] = __builtin_nontemporal_load(rgb4 + 1);   // g1 b1 r2 g2
        c2[k] = __builtin_nontemporal_load(rgb4 + 2);   // b2 r3 g3 b3
    }

    #pragma unroll
    for (int k = 0; k < CPW; ++k) {
        if (!live[k]) break;
        const long long ch  = chunk0 + k;
        const long long ray = ch * 4 + row;

        // ---- deltas ----
        const float zn = dpp_mov<DPP_ROW_SHL(1)>(zz[k].x, 0.0f); // next lane z0
        const float d0 = zz[k].y - zz[k].x;
        const float d1 = zz[k].z - zz[k].y;
        const float d2 = zz[k].w - zz[k].z;
        const float d3 = (j == 15) ? DELTA_INF_V : (zn - zz[k].w);

        // ---- alpha = 1 - exp(-delta * relu(sigma)) ----
        const float a0 = 1.0f - __expf(-d0 * fmaxf(sg[k].x, 0.0f));
        const float a1 = 1.0f - __expf(-d1 * fmaxf(sg[k].y, 0.0f));
        const float a2 = 1.0f - __expf(-d2 * fmaxf(sg[k].z, 0.0f));
        const float a3 = 1.0f - __expf(-d3 * fmaxf(sg[k].w, 0.0f));

        // ---- exclusive cumprod of (1 - a + eps) ----
        const float q0 = 1.0f - a0 + EPS_W;
        const float q1 = 1.0f - a1 + EPS_W;
        const float q2 = 1.0f - a2 + EPS_W;
        const float q3 = 1.0f - a3 + EPS_W;
        const float P0 = q0;
        const float P1 = P0 * q1;
        const float P2 = P1 * q2;
        const float P3 = P2 * q3;

        const float R = row_scan_mul(P3);
        const float E = dpp_mov<DPP_ROW_SHR(1)>(R, 1.0f);  // lane0 = 1

        const float w0 = a0 * E;
        const float w1 = a1 * (E * P0);
        const float w2 = a2 * (E * P1);
        const float w3 = a3 * (E * P2);

        // ---- weights: one contiguous nt float4 store per lane ----
        f4 wv; wv.x = w0; wv.y = w1; wv.z = w2; wv.w = w3;
        __builtin_nontemporal_store(
            wv, reinterpret_cast<f4*>(weights_out + ch * 256) + lane);

        // ---- weighted sums (rgb + depth) ----
        float pr = w0 * c0[k].x + w1 * c0[k].w + w2 * c1[k].z + w3 * c2[k].y;
        float pg = w0 * c0[k].y + w1 * c1[k].x + w2 * c1[k].w + w3 * c2[k].z;
        float pb = w0 * c0[k].z + w1 * c1[k].y + w2 * c2[k].x + w3 * c2[k].w;
        float pd = w0 * zz[k].x + w1 * zz[k].y + w2 * zz[k].z + w3 * zz[k].w;

        pr = row_sum(pr);
        pg = row_sum(pg);
        pb = row_sum(pb);
        pd = row_sum(pd);

        if (j == 15) {
            __builtin_nontemporal_store(pr, rgb_out + ray * 3 + 0);
            __builtin_nontemporal_store(pg, rgb_out + ray * 3 + 1);
            __builtin_nontemporal_store(pb, rgb_out + ray * 3 + 2);
            __builtin_nontemporal_store(pd, depth_out + ray);
        }
    }
}

extern "C" void kernel_launch(void* const* d_in, const int* in_sizes, int n_in,
                              void* d_out, int out_size, void* d_ws, size_t ws_size,
                              hipStream_t stream) {
    const float* rgb    = (const float*)d_in[0];   // [B,R,S,3]
    const float* sigma  = (const float*)d_in[1];   // [B,R,S,1]
    const float* z_vals = (const float*)d_in[2];   // [B,R,S,1]

    const int n_rays = in_sizes[1] / 64;           // B*R = 131072

    float* out         = (float*)d_out;
    float* rgb_out     = out;                              // n_rays*3
    float* depth_out   = out + (long long)n_rays * 3;      // n_rays
    float* weights_out = out + (long long)n_rays * 4;      // n_rays*64

    const int block = 256;                         // 4 waves/block
    const int rays_per_block = (block / 64) * 4 * CPW;   // 32
    const int grid = (n_rays + rays_per_block - 1) / rays_per_block;  // 4096

    volrend_kernel<<<grid, block, 0, stream>>>(
        rgb, sigma, z_vals, rgb_out, depth_out, weights_out, n_rays);
}